// Round 9
// baseline (206.319 us; speedup 1.0000x reference)
//
#include <hip/hip_runtime.h>
#include <math.h>

#define EMBED 512
#define HDIM 64
#define NHEADS 8
#define SEQ_N 2048
#define SEQ_L 2048
#define BATCH 4
#define MROWS (SEQ_N*BATCH)   // 8192 rows, row index m = n*BATCH + b
#define BE (BATCH*EMBED)      // 2048 element row stride in (n,b,E) tensors

// scores scale folded into Q-projection and pe1: 1/sqrt(64) * log2(e)
#define QSCALE 0.18033688f

typedef _Float16 f16;
typedef _Float16 half8 __attribute__((ext_vector_type(8)));
typedef _Float16 half4 __attribute__((ext_vector_type(4)));
typedef _Float16 half2v __attribute__((ext_vector_type(2)));
typedef float floatx4 __attribute__((ext_vector_type(4)));
typedef float floatx16 __attribute__((ext_vector_type(16)));

static __device__ inline float fast_exp2(float x) {
#if __has_builtin(__builtin_amdgcn_exp2f)
  return __builtin_amdgcn_exp2f(x);
#else
  return __expf(x * 0.69314718056f);
#endif
}

static __device__ inline half2v pk2(float a, float b) {
#if __has_builtin(__builtin_amdgcn_cvt_pkrtz)
  return __builtin_bit_cast(half2v, __builtin_amdgcn_cvt_pkrtz(a, b));
#else
  half2v o; o[0] = (f16)a; o[1] = (f16)b; return o;
#endif
}

// async global->LDS 16B/lane copy: LDS dest is wave-uniform base + lane*16.
static __device__ inline void gload16(const void* g, void* l) {
  __builtin_amdgcn_global_load_lds(
      (__attribute__((address_space(1))) void*)(g),
      (__attribute__((address_space(3))) void*)(l), 16, 0, 0);
}

// ---------------------------------------- fused fp32->fp16 converts (1 launch)
__global__ __launch_bounds__(256) void cvt_all(const float* __restrict__ q,
                                               const float* __restrict__ k,
                                               const float* __restrict__ v,
                                               const float* __restrict__ Wq,
                                               const float* __restrict__ Wk,
                                               const float* __restrict__ Wv,
                                               const float* __restrict__ Wo,
                                               f16* __restrict__ qb, f16* __restrict__ kb,
                                               f16* __restrict__ vb, f16* __restrict__ Wb) {
  const long TOK = (long)MROWS * EMBED;
  const long WSZ = (long)EMBED * EMBED;  // 2^18
  int y = blockIdx.y;
  long i = ((long)blockIdx.x * 256 + threadIdx.x) * 4;
  if (y < 3) {
    if (i < TOK) {
      const float* s = y == 0 ? q : y == 1 ? k : v;
      f16* d = y == 0 ? qb : y == 1 ? kb : vb;
      float4 f = *reinterpret_cast<const float4*>(s + i);
      half4 o; o[0] = (f16)f.x; o[1] = (f16)f.y; o[2] = (f16)f.z; o[3] = (f16)f.w;
      *reinterpret_cast<half4*>(d + i) = o;
    }
  } else {
    if (i < 4 * WSZ) {
      int sel = (int)(i >> 18);
      long off = i & (WSZ - 1);
      const float* s = sel == 0 ? Wq : sel == 1 ? Wk : sel == 2 ? Wv : Wo;
      float4 f = *reinterpret_cast<const float4*>(s + off);
      half4 o; o[0] = (f16)f.x; o[1] = (f16)f.y; o[2] = (f16)f.z; o[3] = (f16)f.w;
      *reinterpret_cast<half4*>(Wb + i) = o;
    }
  }
}

// ---------------------------------------- fused QKV projection GEMM (128x128)
// m97-style async global_load_lds staging. sel = y>>2 picks {q,k,v};
// n0 = (y&3)*128. sel==0 pre-scaled QSCALE. sel==2: V transposed per head into
// vt[((b*8+h)*64+d)*2048 + l] via LDS-staged COALESCED epilogue (round 9 —
// replaces the 2B-scattered stores that dominated the non-attn residual).
#define TST 136   // Ts col stride (f16): 16B-aligned (272 B)
__global__ __launch_bounds__(256) void gemm_qkv(const f16* __restrict__ A0,
                                                const f16* __restrict__ A1,
                                                const f16* __restrict__ A2,
                                                const f16* __restrict__ W0,
                                                const f16* __restrict__ W1,
                                                const f16* __restrict__ W2,
                                                const float* __restrict__ b0,
                                                const float* __restrict__ b1,
                                                const float* __restrict__ b2,
                                                f16* __restrict__ C0, f16* __restrict__ C1,
                                                f16* __restrict__ C2t) {
  __shared__ alignas(16) f16 As[128 * 32];
  __shared__ alignas(16) f16 Bs[128 * 32];
  __shared__ alignas(16) f16 Ts[128 * TST];  // transpose buffer (sel==2)
  const int sel = blockIdx.y >> 2;
  const f16* A = sel == 0 ? A0 : sel == 1 ? A1 : A2;
  const f16* Bt = sel == 0 ? W0 : sel == 1 ? W1 : W2;
  const float* bias = sel == 0 ? b0 : sel == 1 ? b1 : b2;
  const float scl = sel == 0 ? QSCALE : 1.0f;
  const int tid = threadIdx.x;
  const int wave = tid >> 6, lane = tid & 63, quad = lane >> 4, l16 = lane & 15;
  const int wm = wave & 1, wn = wave >> 1;
  const long m0 = (long)blockIdx.x * 128;
  const long n0 = (long)(blockIdx.y & 3) * 128;
  floatx4 acc[4][4] = {};
  const int srow = lane >> 2;        // 0..15 row within 16-row chunk
  const int scol = (lane & 3) * 8;   // f16 col within 32-wide tile

  for (int k0 = 0; k0 < EMBED; k0 += 32) {
    __syncthreads();
    gload16(A + (m0 + wave * 32 + srow) * EMBED + k0 + scol, &As[(wave * 32) * 32]);
    gload16(A + (m0 + wave * 32 + 16 + srow) * EMBED + k0 + scol, &As[(wave * 32 + 16) * 32]);
    gload16(Bt + (n0 + wave * 32 + srow) * EMBED + k0 + scol, &Bs[(wave * 32) * 32]);
    gload16(Bt + (n0 + wave * 32 + 16 + srow) * EMBED + k0 + scol, &Bs[(wave * 32 + 16) * 32]);
    __syncthreads();
    half8 af[4], bf[4];
#pragma unroll
    for (int i = 0; i < 4; ++i)
      af[i] = *reinterpret_cast<const half8*>(&As[(wm * 64 + i * 16 + l16) * 32 + quad * 8]);
#pragma unroll
    for (int j = 0; j < 4; ++j)
      bf[j] = *reinterpret_cast<const half8*>(&Bs[(wn * 64 + j * 16 + l16) * 32 + quad * 8]);
#pragma unroll
    for (int i = 0; i < 4; ++i)
#pragma unroll
      for (int j = 0; j < 4; ++j)
        acc[i][j] = __builtin_amdgcn_mfma_f32_16x16x32_f16(af[i], bf[j], acc[i][j], 0, 0, 0);
  }

  if (sel == 2) {
    // write into Ts[col][bq*32 + ltok]: bq = r, ltok = wm*16 + i*4 + quad
#pragma unroll
    for (int i = 0; i < 4; ++i)
#pragma unroll
      for (int r = 0; r < 4; ++r) {
        int ltok = wm * 16 + i * 4 + quad;
#pragma unroll
        for (int j = 0; j < 4; ++j) {
          int col = wn * 64 + j * 16 + l16;
          float val = acc[i][j][r] + bias[n0 + col];
          Ts[col * TST + r * 32 + ltok] = (f16)val;
        }
      }
    __syncthreads();
    // coalesced store: 512 (col,bq) chunks of 32 consecutive ltok (64 B each)
    const long ltok0 = m0 >> 2;
    for (int e = tid; e < 512; e += 256) {
      int col = e >> 2, bq = e & 3;
      long gcol = n0 + col;
      long hh = gcol >> 6, dd = gcol & 63;
      const f16* src = &Ts[col * TST + bq * 32];
      f16* dst = C2t + ((((long)bq << 3) + hh) * 64 + dd) * 2048 + ltok0;
#pragma unroll
      for (int x = 0; x < 4; ++x)
        *reinterpret_cast<uint4*>(dst + x * 8) =
            *reinterpret_cast<const uint4*>(src + x * 8);
    }
  } else {
    f16* C = sel == 0 ? C0 : C1;
#pragma unroll
    for (int i = 0; i < 4; ++i)
#pragma unroll
      for (int r = 0; r < 4; ++r) {
        long row = m0 + wm * 64 + i * 16 + quad * 4 + r;
#pragma unroll
        for (int j = 0; j < 4; ++j) {
          long col = n0 + wn * 64 + j * 16 + l16;
          C[row * EMBED + col] = (f16)((acc[i][j][r] + bias[col]) * scl);
        }
      }
  }
}

// ------------------------------ output GEMM (128x64, f16 in, fp32 out, m97-style)
__global__ __launch_bounds__(256) void gemm_out(const f16* __restrict__ A,
                                                const f16* __restrict__ Bt,
                                                const float* __restrict__ bias,
                                                float* __restrict__ C) {
  __shared__ alignas(16) f16 As[128 * 32];
  __shared__ alignas(16) f16 Bs[64 * 32];
  const int tid = threadIdx.x;
  const int wave = tid >> 6, lane = tid & 63, quad = lane >> 4, l16 = lane & 15;
  const long m0 = (long)blockIdx.x * 128;
  const long n0 = (long)blockIdx.y * 64;
  floatx4 acc[2][4] = {};
  const int srow = lane >> 2;
  const int scol = (lane & 3) * 8;

  for (int k0 = 0; k0 < EMBED; k0 += 32) {
    __syncthreads();
    gload16(A + (m0 + wave * 32 + srow) * EMBED + k0 + scol, &As[(wave * 32) * 32]);
    gload16(A + (m0 + wave * 32 + 16 + srow) * EMBED + k0 + scol, &As[(wave * 32 + 16) * 32]);
    gload16(Bt + (n0 + wave * 16 + srow) * EMBED + k0 + scol, &Bs[(wave * 16) * 32]);
    __syncthreads();
    half8 af[2], bf[4];
#pragma unroll
    for (int i = 0; i < 2; ++i)
      af[i] = *reinterpret_cast<const half8*>(&As[(wave * 32 + i * 16 + l16) * 32 + quad * 8]);
#pragma unroll
    for (int j = 0; j < 4; ++j)
      bf[j] = *reinterpret_cast<const half8*>(&Bs[(j * 16 + l16) * 32 + quad * 8]);
#pragma unroll
    for (int i = 0; i < 2; ++i)
#pragma unroll
      for (int j = 0; j < 4; ++j)
        acc[i][j] = __builtin_amdgcn_mfma_f32_16x16x32_f16(af[i], bf[j], acc[i][j], 0, 0, 0);
  }
#pragma unroll
  for (int i = 0; i < 2; ++i)
#pragma unroll
    for (int r = 0; r < 4; ++r) {
      long row = m0 + wave * 32 + i * 16 + quad * 4 + r;
#pragma unroll
      for (int j = 0; j < 4; ++j) {
        long col = n0 + j * 16 + l16;
        C[row * EMBED + col] = acc[i][j][r] + bias[col];
      }
    }
}

// ------------------------------------------------------------- flash attention
// grid = (N/128, B*H), 512 threads = 8 waves; wave-pair (w, w+4) shares q-strip
// (w&3)*32, half = w>>2 takes l-tiles {0,1} / {2,3}. S^T via mfma_32x32x16,
// P feeds mfma_32x32x8 B-operand from registers. Round 9: LDS DOUBLE-BUFFER,
// single barrier per chunk (stage c+1 into buf[~c] before computing c).
#define KST 88    // Ks row stride (f16)
#define VST 136   // Vt row stride (f16)
#define NCHUNK (SEQ_L / 128)
#define BUFE (128 * KST + 64 * VST)            // 19968 f16 per buffer
__global__ __launch_bounds__(512, 4) void attn_flash(const f16* __restrict__ qp,
                                                     const f16* __restrict__ kp,
                                                     const f16* __restrict__ vt,
                                                     const float* __restrict__ pe1,
                                                     const float* __restrict__ pe2,
                                                     f16* __restrict__ ao) {
  __shared__ alignas(16) f16 smem[2 * BUFE];   // 79872 B -> 2 blocks/CU
  float* comb = reinterpret_cast<float*>(smem);  // merge region (aliases buf0)
  const int tid = threadIdx.x, wave = tid >> 6, lane = tid & 63;
  const int m = lane & 31, h = lane >> 5;
  const int strip = wave & 3, half = wave >> 2;
  const int n0 = blockIdx.x * 128;
  const int b = blockIdx.y >> 3, hd = blockIdx.y & 7;
  const long headoff = (long)b * EMBED + hd * HDIM;
  const long vhead = (long)blockIdx.y * 64 * 2048;

  // ---- preamble: Q through buf0's Ks region; zero pads in BOTH buffers
  f16* Ks0 = smem;
  for (int c = tid; c < 1024; c += 512) {
    int r = c >> 3, col = (c & 7) * 8;
    *reinterpret_cast<uint4*>(&Ks0[r * KST + col]) =
        *reinterpret_cast<const uint4*>(qp + (long)(n0 + r) * BE + headoff + col);
  }
  {
    const uint4 z4 = {0, 0, 0, 0};
    const uint2 z2 = {0, 0};
    int r = tid >> 2, s = tid & 3;
#pragma unroll
    for (int bb = 0; bb < 2; ++bb) {
      f16* Kb = smem + bb * BUFE;
      if (s == 0) *reinterpret_cast<uint2*>(&Kb[r * KST + 68]) = z2;
      else if (s == 1) *reinterpret_cast<uint4*>(&Kb[r * KST + 72]) = z4;
      else if (s == 2) *reinterpret_cast<uint4*>(&Kb[r * KST + 80]) = z4;
    }
  }
  if (tid < 128) {
    long base = ((long)b * SEQ_N + n0 + tid) * 3;
    half4 v8;
    v8[0] = (f16)(pe1[base + 0] * QSCALE);
    v8[1] = (f16)(pe1[base + 1] * QSCALE);
    v8[2] = (f16)(pe1[base + 2] * QSCALE);
    v8[3] = (f16)0.f;
    *reinterpret_cast<half4*>(&Ks0[tid * KST + 64]) = v8;
  }
  __syncthreads();

  half8 qf[5];
#pragma unroll
  for (int e = 0; e < 5; ++e)
    qf[e] = *reinterpret_cast<const half8*>(&Ks0[(strip * 32 + m) * KST + e * 16 + h * 8]);
  __syncthreads();  // Q reads done; buf0 reusable

  // stage chunk 0 into buf0
  auto stage = [&](int l0, f16* KsD, f16* VtD) {
    for (int c = tid; c < 1024; c += 512) {
      int r = c >> 3, col = (c & 7) * 8;
      *reinterpret_cast<uint4*>(&KsD[r * KST + col]) =
          *reinterpret_cast<const uint4*>(kp + (long)(l0 + r) * BE + headoff + col);
      int rv = c >> 4, cv = (c & 15) * 8;
      *reinterpret_cast<uint4*>(&VtD[rv * VST + cv]) =
          *reinterpret_cast<const uint4*>(vt + vhead + (long)rv * 2048 + l0 + cv);
    }
    if (tid < 128) {
      long bb = (long)(l0 + tid) * 3;
      half4 p2;
      p2[0] = (f16)pe2[bb + 0]; p2[1] = (f16)pe2[bb + 1];
      p2[2] = (f16)pe2[bb + 2]; p2[3] = (f16)0.f;
      *reinterpret_cast<half4*>(&KsD[tid * KST + 64]) = p2;
    }
  };
  stage(0, smem, smem + 128 * KST);
  __syncthreads();

  floatx16 oacc[2] = {};
  float lpart = 0.f;

#pragma unroll 1
  for (int c = 0; c < NCHUNK; ++c) {
    // stage next chunk into the other buffer (no barrier needed before compute:
    // writes go to buf[~c], compute reads buf[c]; end-of-iter barrier covers all)
    if (c + 1 < NCHUNK) {
      f16* nb = smem + ((c + 1) & 1) * BUFE;
      stage((c + 1) * 128, nb, nb + 128 * KST);
    }
    const f16* Ks = smem + (c & 1) * BUFE;
    const f16* Vt = Ks + 128 * KST;
#pragma unroll
    for (int tt = 0; tt < 2; ++tt) {
      const int t = half * 2 + tt;
      floatx16 st = {};
#pragma unroll
      for (int e = 0; e < 5; ++e) {
        half8 kf = *reinterpret_cast<const half8*>(&Ks[(t * 32 + m) * KST + e * 16 + h * 8]);
        st = __builtin_amdgcn_mfma_f32_32x32x16_f16(kf, qf[e], st, 0, 0, 0);
      }
      float p[16];
#pragma unroll
      for (int r = 0; r < 16; ++r) {
        p[r] = fast_exp2(st[r]);
        lpart += p[r];
      }
#pragma unroll
      for (int s = 0; s < 4; ++s) {
        half2v u0 = pk2(p[4 * s + 0], p[4 * s + 1]);
        half2v u1 = pk2(p[4 * s + 2], p[4 * s + 3]);
        half4 bp;
        bp[0] = u0[0]; bp[1] = u0[1]; bp[2] = u1[0]; bp[3] = u1[1];
        int lcol = t * 32 + s * 8 + h * 4;
#pragma unroll
        for (int dt = 0; dt < 2; ++dt) {
          half4 vf = *reinterpret_cast<const half4*>(&Vt[(dt * 32 + m) * VST + lcol]);
          oacc[dt] = __builtin_amdgcn_mfma_f32_32x32x8f16(vf, bp, oacc[dt], 0, 0, 0);
        }
      }
    }
    __syncthreads();  // chunk c reads done; chunk c+1 staging visible
  }

  lpart += __shfl_xor(lpart, 32);

  if (half == 1) {
    float* dst = comb + (strip * 64 + lane) * 33;
#pragma unroll
    for (int dt = 0; dt < 2; ++dt)
#pragma unroll
      for (int x = 0; x < 16; ++x) dst[dt * 16 + x] = oacc[dt][x];
    dst[32] = lpart;
  }
  __syncthreads();
  if (half == 0) {
    const float* src = comb + (strip * 64 + lane) * 33;
#pragma unroll
    for (int dt = 0; dt < 2; ++dt)
#pragma unroll
      for (int x = 0; x < 16; ++x) oacc[dt][x] += src[dt * 16 + x];
    float inv = 1.f / (lpart + src[32]);
    long qrow = n0 + strip * 32 + m;
#pragma unroll
    for (int dt = 0; dt < 2; ++dt)
#pragma unroll
      for (int g = 0; g < 4; ++g) {
        half4 o4;
#pragma unroll
        for (int x = 0; x < 4; ++x) o4[x] = (f16)(oacc[dt][4 * g + x] * inv);
        int d = dt * 32 + 8 * g + 4 * h;
        *reinterpret_cast<half4*>(ao + qrow * BE + headoff + d) = o4;
      }
  }
}

// ---------------------------------------------------------------------- launch
extern "C" void kernel_launch(void* const* d_in, const int* in_sizes, int n_in,
                              void* d_out, int out_size, void* d_ws, size_t ws_size,
                              hipStream_t stream) {
  const float* q   = (const float*)d_in[0];
  const float* k   = (const float*)d_in[1];
  const float* v   = (const float*)d_in[2];
  const float* pe1 = (const float*)d_in[3];
  const float* pe2 = (const float*)d_in[4];
  const float* Wq  = (const float*)d_in[5];
  const float* bq  = (const float*)d_in[6];
  const float* Wk  = (const float*)d_in[7];
  const float* bk  = (const float*)d_in[8];
  const float* Wv  = (const float*)d_in[9];
  const float* bv  = (const float*)d_in[10];
  const float* Wo  = (const float*)d_in[11];
  const float* bo  = (const float*)d_in[12];
  float* out = (float*)d_out;

  f16* ws = (f16*)d_ws;
  const long TOK = (long)MROWS * EMBED;  // 4,194,304 elements
  const long WSZ = (long)EMBED * EMBED;  //   262,144 elements
  f16* qb  = ws;
  f16* kb  = qb + TOK;
  f16* vb  = kb + TOK;
  f16* Wqb = vb + TOK;          // 4 weights contiguous: Wq,Wk,Wv,Wo
  f16* Wkb = Wqb + WSZ;
  f16* Wvb = Wkb + WSZ;
  f16* Wob = Wvb + WSZ;
  f16* qpb = Wob + WSZ;
  f16* kpb = qpb + TOK;
  f16* vtb = kpb + TOK;         // transposed-V (written by gemm_qkv sel==2)
  f16* aob = vtb + TOK;         // ~61 MB total

  cvt_all<<<dim3(4096, 4), 256, 0, stream>>>(q, k, v, Wq, Wk, Wv, Wo, qb, kb, vb, Wqb);

  gemm_qkv<<<dim3(MROWS / 128, 12), 256, 0, stream>>>(qb, kb, vb, Wqb, Wkb, Wvb,
                                                      bq, bk, bv, qpb, kpb, vtb);

  attn_flash<<<dim3(SEQ_N / 128, BATCH * NHEADS), 512, 0, stream>>>(qpb, kpb, vtb, pe1, pe2, aob);

  gemm_out<<<dim3(MROWS / 128, EMBED / 64), 256, 0, stream>>>(aob, Wob, bo, out);
}